// Round 1
// baseline (835.296 us; speedup 1.0000x reference)
//
#include <hip/hip_runtime.h>
#include <hip/hip_bf16.h>

#define B_   8
#define NMAX 8192
#define C_   384
#define G_   512
#define K_   32
#define H_   6
#define DH_  64

typedef short bvec8 __attribute__((ext_vector_type(8)));
typedef short bvec4 __attribute__((ext_vector_type(4)));
typedef float f32x4 __attribute__((ext_vector_type(4)));

__device__ __forceinline__ short f2bf(float f) {
    union { __hip_bfloat16 b; short s; } u;
    u.b = __float2bfloat16(f);
    return u.s;
}

// ---- LDS layout (bytes) ----
// [0, 24576)              xg (later attn_out)  [32 rows][768 B] XOR-swizzled
// [24576 + h*12288 + 0)   qbuf (later P)       [32][128 B] swizzled
// [        ... + 4096)    kbuf                 [32][128 B] swizzled
// [        ... + 8192)    vT                   [64][64 B]  swizzled ((dh&3)<<4)
// [98304)                 mask  32 f32
// [98432)                 idx   32 i32
#define LDS_BYTES 98560

__device__ __forceinline__ int swzA(int row, int colb) { return row * 768 + (colb ^ ((row & 7) << 4)); }
__device__ __forceinline__ int swzQ(int row, int colb) { return row * 128 + (colb ^ ((row & 7) << 4)); }
__device__ __forceinline__ int swzV(int dh,  int colb) { return dh  * 64  + (colb ^ ((dh  & 3) << 4)); }

__global__ void convw_kernel(const float* __restrict__ wqkv, const float* __restrict__ wproj,
                             short* __restrict__ wq_bf, short* __restrict__ wp_bf) {
    int i = blockIdx.x * 256 + threadIdx.x;
    if (i < 3 * C_ * C_) wq_bf[i] = f2bf(wqkv[i]);
    if (i < C_ * C_)     wp_bf[i] = f2bf(wproj[i]);
}

__global__ __launch_bounds__(384, 1) void attn_kernel(
    const float* __restrict__ feats, const int* __restrict__ gidx,
    const float* __restrict__ gmask, const short* __restrict__ wqkv,
    const short* __restrict__ wproj, const float* __restrict__ bproj,
    float* __restrict__ acc_out, float* __restrict__ cnt) {
    extern __shared__ char sm[];
    float* mask_lds = (float*)(sm + 98304);
    int*   idx_lds  = (int*)(sm + 98432);

    const int tid  = threadIdx.x;
    const int lane = tid & 63;
    const int h    = tid >> 6;          // wave id = head id (0..5)
    const int bg   = blockIdx.x;        // group id within [0, B*G)
    const int b    = bg >> 9;
    const int l15  = lane & 15;
    const int l4   = lane >> 4;

    if (tid < 32) {
        int v = gidx[(size_t)bg * K_ + tid];
        v = v < 0 ? 0 : v;
        float m = gmask[(size_t)bg * K_ + tid];
        idx_lds[tid]  = v;
        mask_lds[tid] = m;
        if (m > 0.f) atomicAdd(&cnt[b * NMAX + v], m);
    }
    __syncthreads();

    // ---- gather: 32 rows x 384 fp32 -> bf16 LDS (swizzled) ----
    #pragma unroll
    for (int i = 0; i < 8; ++i) {
        int p = i * 384 + tid;          // 0..3071 tasks, one float4 each
        int row = p / 96, seg = p % 96;
        float4 f = *(const float4*)(feats + ((size_t)(b * NMAX + idx_lds[row]) * C_ + seg * 4));
        bvec4 v4 = { f2bf(f.x), f2bf(f.y), f2bf(f.z), f2bf(f.w) };
        *(bvec4*)(sm + swzA(row, seg * 8)) = v4;
    }
    __syncthreads();

    char* qb = sm + 24576 + h * 12288;
    char* kb = qb + 4096;
    char* vb = qb + 8192;

    // ---- QKV: three passes (q, k, v), each [32 x 64] = xg[32x384] @ W^T ----
    for (int mat = 0; mat < 3; ++mat) {
        f32x4 acc[2][4];
        #pragma unroll
        for (int mt = 0; mt < 2; ++mt)
            #pragma unroll
            for (int nt = 0; nt < 4; ++nt) acc[mt][nt] = (f32x4){0.f, 0.f, 0.f, 0.f};

        const short* wbase = wqkv + ((size_t)(mat * C_ + h * DH_)) * C_;
        #pragma unroll
        for (int kk = 0; kk < 12; ++kk) {
            bvec8 a0 = *(const bvec8*)(sm + swzA(l15,      kk * 64 + l4 * 16));
            bvec8 a1 = *(const bvec8*)(sm + swzA(16 + l15, kk * 64 + l4 * 16));
            #pragma unroll
            for (int nt = 0; nt < 4; ++nt) {
                bvec8 bf = *(const bvec8*)(wbase + (size_t)(nt * 16 + l15) * C_ + kk * 32 + l4 * 8);
                acc[0][nt] = __builtin_amdgcn_mfma_f32_16x16x32_bf16(a0, bf, acc[0][nt], 0, 0, 0);
                acc[1][nt] = __builtin_amdgcn_mfma_f32_16x16x32_bf16(a1, bf, acc[1][nt], 0, 0, 0);
            }
        }

        if (mat < 2) {
            // q (scaled by 1/8, exact) and k stored [token][64 dh] bf16, swizzled
            char* dst = (mat == 0) ? qb : kb;
            float scl = (mat == 0) ? 0.125f : 1.0f;
            #pragma unroll
            for (int mt = 0; mt < 2; ++mt)
                #pragma unroll
                for (int nt = 0; nt < 4; ++nt)
                    #pragma unroll
                    for (int j = 0; j < 4; ++j) {
                        int r = mt * 16 + l4 * 4 + j, c = nt * 16 + l15;
                        *(short*)(dst + swzQ(r, c * 2)) = f2bf(acc[mt][nt][j] * scl);
                    }
        } else {
            // v stored transposed: vT[dh][token] bf16 (packs 4 consecutive tokens)
            #pragma unroll
            for (int mt = 0; mt < 2; ++mt)
                #pragma unroll
                for (int nt = 0; nt < 4; ++nt) {
                    int dh = nt * 16 + l15, t0 = mt * 16 + l4 * 4;
                    bvec4 v4 = { f2bf(acc[mt][nt][0]), f2bf(acc[mt][nt][1]),
                                 f2bf(acc[mt][nt][2]), f2bf(acc[mt][nt][3]) };
                    *(bvec4*)(vb + swzV(dh, t0 * 2)) = v4;
                }
        }
    }
    __syncthreads();   // all xg reads done before attn_out overwrites buffer

    // ---- scores = q @ k^T  ([32 x 32], scale folded into q) ----
    f32x4 sc[2][2];
    #pragma unroll
    for (int mt = 0; mt < 2; ++mt)
        #pragma unroll
        for (int nt = 0; nt < 2; ++nt) sc[mt][nt] = (f32x4){0.f, 0.f, 0.f, 0.f};
    #pragma unroll
    for (int kk = 0; kk < 2; ++kk) {
        bvec8 a0 = *(const bvec8*)(qb + swzQ(l15,      kk * 64 + l4 * 16));
        bvec8 a1 = *(const bvec8*)(qb + swzQ(16 + l15, kk * 64 + l4 * 16));
        bvec8 b0 = *(const bvec8*)(kb + swzQ(l15,      kk * 64 + l4 * 16));
        bvec8 b1 = *(const bvec8*)(kb + swzQ(16 + l15, kk * 64 + l4 * 16));
        sc[0][0] = __builtin_amdgcn_mfma_f32_16x16x32_bf16(a0, b0, sc[0][0], 0, 0, 0);
        sc[0][1] = __builtin_amdgcn_mfma_f32_16x16x32_bf16(a0, b1, sc[0][1], 0, 0, 0);
        sc[1][0] = __builtin_amdgcn_mfma_f32_16x16x32_bf16(a1, b0, sc[1][0], 0, 0, 0);
        sc[1][1] = __builtin_amdgcn_mfma_f32_16x16x32_bf16(a1, b1, sc[1][1], 0, 0, 0);
    }

    // ---- softmax over keys (row-wise), P written back into qb (bf16) ----
    float bias0 = mask_lds[l15]      > 0.f ? 0.f : -1e30f;
    float bias1 = mask_lds[16 + l15] > 0.f ? 0.f : -1e30f;
    #pragma unroll
    for (int mt = 0; mt < 2; ++mt)
        #pragma unroll
        for (int j = 0; j < 4; ++j) {
            float s0 = sc[mt][0][j] + bias0;
            float s1 = sc[mt][1][j] + bias1;
            float m = fmaxf(s0, s1);
            #pragma unroll
            for (int off = 8; off >= 1; off >>= 1) m = fmaxf(m, __shfl_xor(m, off, 16));
            float p0 = __expf(s0 - m), p1 = __expf(s1 - m);
            float ssum = p0 + p1;
            #pragma unroll
            for (int off = 8; off >= 1; off >>= 1) ssum += __shfl_xor(ssum, off, 16);
            float inv = 1.f / ssum;
            int r = mt * 16 + l4 * 4 + j;
            *(short*)(qb + swzQ(r, l15 * 2))        = f2bf(p0 * inv);
            *(short*)(qb + swzQ(r, (16 + l15) * 2)) = f2bf(p1 * inv);
        }

    // ---- PV: out_h[32 x 64] = P @ v ----
    f32x4 po[2][4];
    #pragma unroll
    for (int mt = 0; mt < 2; ++mt)
        #pragma unroll
        for (int nt = 0; nt < 4; ++nt) po[mt][nt] = (f32x4){0.f, 0.f, 0.f, 0.f};
    {
        bvec8 pa0 = *(const bvec8*)(qb + swzQ(l15,      l4 * 16));
        bvec8 pa1 = *(const bvec8*)(qb + swzQ(16 + l15, l4 * 16));
        #pragma unroll
        for (int nt = 0; nt < 4; ++nt) {
            bvec8 bv = *(const bvec8*)(vb + swzV(nt * 16 + l15, l4 * 16));
            po[0][nt] = __builtin_amdgcn_mfma_f32_16x16x32_bf16(pa0, bv, po[0][nt], 0, 0, 0);
            po[1][nt] = __builtin_amdgcn_mfma_f32_16x16x32_bf16(pa1, bv, po[1][nt], 0, 0, 0);
        }
    }
    // write attn_out (bf16) into the xg buffer, columns h*64 .. h*64+63
    #pragma unroll
    for (int mt = 0; mt < 2; ++mt)
        #pragma unroll
        for (int nt = 0; nt < 4; ++nt)
            #pragma unroll
            for (int j = 0; j < 4; ++j) {
                int r = mt * 16 + l4 * 4 + j, c = h * DH_ + nt * 16 + l15;
                *(short*)(sm + swzA(r, c * 2)) = f2bf(po[mt][nt][j]);
            }
    __syncthreads();

    // ---- proj: out[32 x 384] = attn_out @ w_proj^T + b_proj ; wave h -> cols h*64.. ----
    f32x4 pr[2][4];
    #pragma unroll
    for (int mt = 0; mt < 2; ++mt)
        #pragma unroll
        for (int nt = 0; nt < 4; ++nt) pr[mt][nt] = (f32x4){0.f, 0.f, 0.f, 0.f};
    #pragma unroll
    for (int kk = 0; kk < 12; ++kk) {
        bvec8 a0 = *(const bvec8*)(sm + swzA(l15,      kk * 64 + l4 * 16));
        bvec8 a1 = *(const bvec8*)(sm + swzA(16 + l15, kk * 64 + l4 * 16));
        #pragma unroll
        for (int nt = 0; nt < 4; ++nt) {
            bvec8 w = *(const bvec8*)(wproj + (size_t)(h * DH_ + nt * 16 + l15) * C_ + kk * 32 + l4 * 8);
            pr[0][nt] = __builtin_amdgcn_mfma_f32_16x16x32_bf16(a0, w, pr[0][nt], 0, 0, 0);
            pr[1][nt] = __builtin_amdgcn_mfma_f32_16x16x32_bf16(a1, w, pr[1][nt], 0, 0, 0);
        }
    }

    // ---- masked scatter-add into acc (d_out) ----
    #pragma unroll
    for (int nt = 0; nt < 4; ++nt) {
        int c = h * DH_ + nt * 16 + l15;
        float bias = bproj[c];
        #pragma unroll
        for (int mt = 0; mt < 2; ++mt)
            #pragma unroll
            for (int j = 0; j < 4; ++j) {
                int t = mt * 16 + l4 * 4 + j;
                float mk = mask_lds[t];
                if (mk > 0.f) {
                    float val = pr[mt][nt][j] + bias;
                    atomicAdd(acc_out + (size_t)(b * NMAX + idx_lds[t]) * C_ + c, val);
                }
            }
    }
}

__global__ void finalize_kernel(const float* __restrict__ feats, const float* __restrict__ cnt,
                                const float* __restrict__ gamma, float* __restrict__ out) {
    size_t i4 = (size_t)blockIdx.x * 256 + threadIdx.x;       // float4 index
    const size_t total4 = (size_t)B_ * NMAX * C_ / 4;
    if (i4 >= total4) return;
    int n  = (int)(i4 / (C_ / 4));
    int c4 = (int)(i4 % (C_ / 4)) * 4;
    float cv = cnt[n];
    float inv = 1.f / (cv < 1.f ? 1.f : cv);
    float4 a = ((const float4*)out)[i4];
    float4 f = ((const float4*)feats)[i4];
    float4 g = *(const float4*)(gamma + c4);
    float4 r;
    r.x = f.x + a.x * inv * g.x;
    r.y = f.y + a.y * inv * g.y;
    r.z = f.z + a.z * inv * g.z;
    r.w = f.w + a.w * inv * g.w;
    ((float4*)out)[i4] = r;
}

extern "C" void kernel_launch(void* const* d_in, const int* in_sizes, int n_in,
                              void* d_out, int out_size, void* d_ws, size_t ws_size,
                              hipStream_t stream) {
    const float* feats = (const float*)d_in[0];
    const int*   gidx  = (const int*)d_in[1];
    const float* gmask = (const float*)d_in[2];
    const float* wqkv  = (const float*)d_in[3];
    const float* wproj = (const float*)d_in[4];
    const float* bproj = (const float*)d_in[5];
    const float* gamma = (const float*)d_in[6];
    float* out = (float*)d_out;

    char* ws = (char*)d_ws;
    short* wq_bf = (short*)ws;                              // 3*384*384*2 = 884736 B
    short* wp_bf = (short*)(ws + 884736);                   // 384*384*2   = 294912 B
    float* cnt   = (float*)(ws + 884736 + 294912);          // 65536*4     = 262144 B

    hipMemsetAsync(out, 0, (size_t)B_ * NMAX * C_ * sizeof(float), stream);
    hipMemsetAsync(cnt, 0, (size_t)B_ * NMAX * sizeof(float), stream);

    convw_kernel<<<(3 * C_ * C_ + 255) / 256, 256, 0, stream>>>(wqkv, wproj, wq_bf, wp_bf);

    attn_kernel<<<B_ * G_, 384, LDS_BYTES, stream>>>(feats, gidx, gmask, wq_bf, wp_bf,
                                                     bproj, out, cnt);

    finalize_kernel<<<(B_ * NMAX * C_ / 4 + 255) / 256, 256, 0, stream>>>(feats, cnt, gamma, out);
}

// Round 2
// 784.156 us; speedup vs baseline: 1.0652x; 1.0652x over previous
//
#include <hip/hip_runtime.h>
#include <hip/hip_bf16.h>

#define B_   8
#define NMAX 8192
#define C_   384
#define G_   512
#define K_   32
#define H_   6
#define DH_  64

typedef short bvec8 __attribute__((ext_vector_type(8)));
typedef short bvec4 __attribute__((ext_vector_type(4)));
typedef _Float16 hvec4 __attribute__((ext_vector_type(4)));
typedef float f32x4 __attribute__((ext_vector_type(4)));

__device__ __forceinline__ short f2bf(float f) {
    union { __hip_bfloat16 b; short s; } u;
    u.b = __float2bfloat16(f);
    return u.s;
}
__device__ __forceinline__ unsigned char f2fp8(float x) {
    return (unsigned char)(__builtin_amdgcn_cvt_pk_fp8_f32(x, x, 0, false) & 0xff);
}

// ---- LDS layout (bytes) ----
// [0, 24576)        xg (later attn_out)  [32 rows][768 B] bf16, XOR-swizzled
// [24576 + h*4096)  qf8 [32][64] fp8 ; +2048: kf8 [32][64] fp8
// [49152) mask 32 f32 ; [49280) idx 32 i32
#define HB_OFF    24576
#define MASK_OFF  49152
#define IDX_OFF   49280
#define LDS_BYTES 49408

__device__ __forceinline__ int swzA(int row, int colb) { return row * 768 + (colb ^ ((row & 7) << 4)); }
__device__ __forceinline__ int swz8(int row, int col)  { return row * 64  + (col  ^ ((row & 7) << 3)); }

__global__ void convw_kernel(const float* __restrict__ wqkv, const float* __restrict__ wproj,
                             short* __restrict__ wq_bf, short* __restrict__ wp_bf) {
    int i = blockIdx.x * 256 + threadIdx.x;
    if (i < 3 * C_ * C_) wq_bf[i] = f2bf(wqkv[i]);
    if (i < C_ * C_)     wp_bf[i] = f2bf(wproj[i]);
}

__global__ __launch_bounds__(384, 5) void attn_kernel(
    const float* __restrict__ feats, const int* __restrict__ gidx,
    const float* __restrict__ gmask, const short* __restrict__ wqkv,
    const short* __restrict__ wproj, const float* __restrict__ bproj,
    float* __restrict__ acc_out, float* __restrict__ cnt) {
    extern __shared__ char sm[];
    float* mask_lds = (float*)(sm + MASK_OFF);
    int*   idx_lds  = (int*)(sm + IDX_OFF);

    const int tid  = threadIdx.x;
    const int lane = tid & 63;
    const int h    = tid >> 6;          // wave id = head id (0..5)
    const int bg   = blockIdx.x;        // group id within [0, B*G)
    const int b    = bg >> 9;
    const int l15  = lane & 15;
    const int l4   = lane >> 4;

    if (tid < 32) {
        int v = gidx[(size_t)bg * K_ + tid];
        v = v < 0 ? 0 : v;
        float m = gmask[(size_t)bg * K_ + tid];
        idx_lds[tid]  = v;
        mask_lds[tid] = m;
        if (m > 0.f) atomicAdd(&cnt[b * NMAX + v], m);
    }
    __syncthreads();

    // ---- gather: 32 rows x 384 fp32 -> bf16 LDS (swizzled) ----
    #pragma unroll
    for (int i = 0; i < 8; ++i) {
        int p = i * 384 + tid;          // 0..3071 tasks, one float4 each
        int row = p / 96, seg = p % 96;
        float4 f = *(const float4*)(feats + ((size_t)(b * NMAX + idx_lds[row]) * C_ + seg * 4));
        bvec4 v4 = { f2bf(f.x), f2bf(f.y), f2bf(f.z), f2bf(f.w) };
        *(bvec4*)(sm + swzA(row, seg * 8)) = v4;
    }
    __syncthreads();

    char* qf = sm + HB_OFF + h * 4096;
    char* kf = qf + 2048;

    // ---- q and k GEMMs: [32 x 64] = xg[32x384] @ W^T  -> fp8 LDS ----
    for (int mat = 0; mat < 2; ++mat) {
        f32x4 acc[2][4];
        #pragma unroll
        for (int mt = 0; mt < 2; ++mt)
            #pragma unroll
            for (int nt = 0; nt < 4; ++nt) acc[mt][nt] = (f32x4){0.f, 0.f, 0.f, 0.f};
        const short* wb = wqkv + ((size_t)(mat * C_ + h * DH_)) * C_;
        #pragma unroll
        for (int kk = 0; kk < 12; ++kk) {
            bvec8 a0 = *(const bvec8*)(sm + swzA(l15,      kk * 64 + l4 * 16));
            bvec8 a1 = *(const bvec8*)(sm + swzA(16 + l15, kk * 64 + l4 * 16));
            #pragma unroll
            for (int nt = 0; nt < 4; ++nt) {
                bvec8 bf = *(const bvec8*)(wb + (size_t)(nt * 16 + l15) * C_ + kk * 32 + l4 * 8);
                acc[0][nt] = __builtin_amdgcn_mfma_f32_16x16x32_bf16(a0, bf, acc[0][nt], 0, 0, 0);
                acc[1][nt] = __builtin_amdgcn_mfma_f32_16x16x32_bf16(a1, bf, acc[1][nt], 0, 0, 0);
            }
        }
        char* dst = mat ? kf : qf;
        #pragma unroll
        for (int mt = 0; mt < 2; ++mt)
            #pragma unroll
            for (int nt = 0; nt < 4; ++nt)
                #pragma unroll
                for (int j = 0; j < 4; ++j) {
                    int r = mt * 16 + l4 * 4 + j, c = nt * 16 + l15;
                    *(unsigned char*)(dst + swz8(r, c)) = f2fp8(acc[mt][nt][j]);
                }
    }

    // ---- v GEMM: keep result in registers as f16 A-fragments ----
    hvec4 vfrag[2][4];
    {
        f32x4 acc[2][4];
        #pragma unroll
        for (int mt = 0; mt < 2; ++mt)
            #pragma unroll
            for (int nt = 0; nt < 4; ++nt) acc[mt][nt] = (f32x4){0.f, 0.f, 0.f, 0.f};
        const short* wb = wqkv + ((size_t)(2 * C_ + h * DH_)) * C_;
        #pragma unroll
        for (int kk = 0; kk < 12; ++kk) {
            bvec8 a0 = *(const bvec8*)(sm + swzA(l15,      kk * 64 + l4 * 16));
            bvec8 a1 = *(const bvec8*)(sm + swzA(16 + l15, kk * 64 + l4 * 16));
            #pragma unroll
            for (int nt = 0; nt < 4; ++nt) {
                bvec8 bf = *(const bvec8*)(wb + (size_t)(nt * 16 + l15) * C_ + kk * 32 + l4 * 8);
                acc[0][nt] = __builtin_amdgcn_mfma_f32_16x16x32_bf16(a0, bf, acc[0][nt], 0, 0, 0);
                acc[1][nt] = __builtin_amdgcn_mfma_f32_16x16x32_bf16(a1, bf, acc[1][nt], 0, 0, 0);
            }
        }
        // vfrag[c][dt]: tokens c*16 + l4*4 + (0..3) at dh = dt*16 + l15
        #pragma unroll
        for (int mt = 0; mt < 2; ++mt)
            #pragma unroll
            for (int nt = 0; nt < 4; ++nt)
                vfrag[mt][nt] = (hvec4){ (_Float16)acc[mt][nt][0], (_Float16)acc[mt][nt][1],
                                         (_Float16)acc[mt][nt][2], (_Float16)acc[mt][nt][3] };
    }

    // ---- scores^T = k @ q^T  (fp8, [32 keys x 32 qtok]) ----
    f32x4 sc[2][2];
    #pragma unroll
    for (int mt = 0; mt < 2; ++mt)
        #pragma unroll
        for (int nt = 0; nt < 2; ++nt) sc[mt][nt] = (f32x4){0.f, 0.f, 0.f, 0.f};
    #pragma unroll
    for (int kk = 0; kk < 2; ++kk) {
        long ka0 = *(const long*)(kf + swz8(l15,      kk * 32 + l4 * 8));
        long ka1 = *(const long*)(kf + swz8(16 + l15, kk * 32 + l4 * 8));
        long qa0 = *(const long*)(qf + swz8(l15,      kk * 32 + l4 * 8));
        long qa1 = *(const long*)(qf + swz8(16 + l15, kk * 32 + l4 * 8));
        sc[0][0] = __builtin_amdgcn_mfma_f32_16x16x32_fp8_fp8(ka0, qa0, sc[0][0], 0, 0, 0);
        sc[0][1] = __builtin_amdgcn_mfma_f32_16x16x32_fp8_fp8(ka0, qa1, sc[0][1], 0, 0, 0);
        sc[1][0] = __builtin_amdgcn_mfma_f32_16x16x32_fp8_fp8(ka1, qa0, sc[1][0], 0, 0, 0);
        sc[1][1] = __builtin_amdgcn_mfma_f32_16x16x32_fp8_fp8(ka1, qa1, sc[1][1], 0, 0, 0);
    }

    // ---- softmax over keys (keys live in-register + across l4 groups) ----
    // lane holds scT[key = mt*16 + l4*4 + j][qtok = nt*16 + l15]
    float bk[2][4];
    #pragma unroll
    for (int mt = 0; mt < 2; ++mt)
        #pragma unroll
        for (int j = 0; j < 4; ++j)
            bk[mt][j] = mask_lds[mt * 16 + l4 * 4 + j] > 0.f ? 0.f : -1e30f;

    hvec4 pfrag[2][2];   // [key chunk c][qtok tile qt]
    #pragma unroll
    for (int nt = 0; nt < 2; ++nt) {
        float s[2][4];
        float mx = -1e30f;
        #pragma unroll
        for (int mt = 0; mt < 2; ++mt)
            #pragma unroll
            for (int j = 0; j < 4; ++j) {
                s[mt][j] = sc[mt][nt][j] * 0.125f + bk[mt][j];
                mx = fmaxf(mx, s[mt][j]);
            }
        mx = fmaxf(mx, __shfl_xor(mx, 16));
        mx = fmaxf(mx, __shfl_xor(mx, 32));
        float sum = 0.f;
        #pragma unroll
        for (int mt = 0; mt < 2; ++mt)
            #pragma unroll
            for (int j = 0; j < 4; ++j) {
                s[mt][j] = __expf(s[mt][j] - mx);
                sum += s[mt][j];
            }
        sum += __shfl_xor(sum, 16);
        sum += __shfl_xor(sum, 32);
        float inv = 1.f / sum;
        #pragma unroll
        for (int mt = 0; mt < 2; ++mt)
            pfrag[mt][nt] = (hvec4){ (_Float16)(s[mt][0] * inv), (_Float16)(s[mt][1] * inv),
                                     (_Float16)(s[mt][2] * inv), (_Float16)(s[mt][3] * inv) };
    }

    // ---- PV: out^T[dh][qtok] via 16x16x16 f16 MFMA, all in registers ----
    f32x4 po[4][2];
    #pragma unroll
    for (int dt = 0; dt < 4; ++dt)
        #pragma unroll
        for (int qt = 0; qt < 2; ++qt) po[dt][qt] = (f32x4){0.f, 0.f, 0.f, 0.f};
    #pragma unroll
    for (int c = 0; c < 2; ++c)
        #pragma unroll
        for (int dt = 0; dt < 4; ++dt)
            #pragma unroll
            for (int qt = 0; qt < 2; ++qt)
                po[dt][qt] = __builtin_amdgcn_mfma_f32_16x16x16f16(vfrag[c][dt], pfrag[c][qt], po[dt][qt], 0, 0, 0);

    __syncthreads();   // all waves done reading xg (v-GEMM) before overwrite

    // write attn_out (bf16) into xg buffer: out^T C-layout -> [tok][channel]
    #pragma unroll
    for (int dt = 0; dt < 4; ++dt)
        #pragma unroll
        for (int qt = 0; qt < 2; ++qt)
            #pragma unroll
            for (int j = 0; j < 4; ++j) {
                int tok = qt * 16 + l15;
                int ch  = h * DH_ + dt * 16 + l4 * 4 + j;
                *(short*)(sm + swzA(tok, ch * 2)) = f2bf(po[dt][qt][j]);
            }
    __syncthreads();

    // ---- proj: out[32 x 384] = attn_out @ w_proj^T ; wave h -> cols h*64.. ----
    f32x4 pr[2][4];
    #pragma unroll
    for (int mt = 0; mt < 2; ++mt)
        #pragma unroll
        for (int nt = 0; nt < 4; ++nt) pr[mt][nt] = (f32x4){0.f, 0.f, 0.f, 0.f};
    #pragma unroll
    for (int kk = 0; kk < 12; ++kk) {
        bvec8 a0 = *(const bvec8*)(sm + swzA(l15,      kk * 64 + l4 * 16));
        bvec8 a1 = *(const bvec8*)(sm + swzA(16 + l15, kk * 64 + l4 * 16));
        #pragma unroll
        for (int nt = 0; nt < 4; ++nt) {
            bvec8 w = *(const bvec8*)(wproj + (size_t)(h * DH_ + nt * 16 + l15) * C_ + kk * 32 + l4 * 8);
            pr[0][nt] = __builtin_amdgcn_mfma_f32_16x16x32_bf16(a0, w, pr[0][nt], 0, 0, 0);
            pr[1][nt] = __builtin_amdgcn_mfma_f32_16x16x32_bf16(a1, w, pr[1][nt], 0, 0, 0);
        }
    }

    // ---- masked scatter-add into acc (d_out) ----
    #pragma unroll
    for (int nt = 0; nt < 4; ++nt) {
        int c = h * DH_ + nt * 16 + l15;
        float bias = bproj[c];
        #pragma unroll
        for (int mt = 0; mt < 2; ++mt)
            #pragma unroll
            for (int j = 0; j < 4; ++j) {
                int t = mt * 16 + l4 * 4 + j;
                float mk = mask_lds[t];
                if (mk > 0.f) {
                    float val = pr[mt][nt][j] + bias;
                    atomicAdd(acc_out + (size_t)(b * NMAX + idx_lds[t]) * C_ + c, val);
                }
            }
    }
}

__global__ void finalize_kernel(const float* __restrict__ feats, const float* __restrict__ cnt,
                                const float* __restrict__ gamma, float* __restrict__ out) {
    size_t i4 = (size_t)blockIdx.x * 256 + threadIdx.x;       // float4 index
    const size_t total4 = (size_t)B_ * NMAX * C_ / 4;
    if (i4 >= total4) return;
    int n  = (int)(i4 / (C_ / 4));
    int c4 = (int)(i4 % (C_ / 4)) * 4;
    float cv = cnt[n];
    float inv = 1.f / (cv < 1.f ? 1.f : cv);
    float4 a = ((const float4*)out)[i4];
    float4 f = ((const float4*)feats)[i4];
    float4 g = *(const float4*)(gamma + c4);
    float4 r;
    r.x = f.x + a.x * inv * g.x;
    r.y = f.y + a.y * inv * g.y;
    r.z = f.z + a.z * inv * g.z;
    r.w = f.w + a.w * inv * g.w;
    ((float4*)out)[i4] = r;
}

extern "C" void kernel_launch(void* const* d_in, const int* in_sizes, int n_in,
                              void* d_out, int out_size, void* d_ws, size_t ws_size,
                              hipStream_t stream) {
    const float* feats = (const float*)d_in[0];
    const int*   gidx  = (const int*)d_in[1];
    const float* gmask = (const float*)d_in[2];
    const float* wqkv  = (const float*)d_in[3];
    const float* wproj = (const float*)d_in[4];
    const float* bproj = (const float*)d_in[5];
    const float* gamma = (const float*)d_in[6];
    float* out = (float*)d_out;

    char* ws = (char*)d_ws;
    short* wq_bf = (short*)ws;                              // 3*384*384*2 = 884736 B
    short* wp_bf = (short*)(ws + 884736);                   // 384*384*2   = 294912 B
    float* cnt   = (float*)(ws + 884736 + 294912);          // 65536*4     = 262144 B

    hipMemsetAsync(out, 0, (size_t)B_ * NMAX * C_ * sizeof(float), stream);
    hipMemsetAsync(cnt, 0, (size_t)B_ * NMAX * sizeof(float), stream);

    convw_kernel<<<(3 * C_ * C_ + 255) / 256, 256, 0, stream>>>(wqkv, wproj, wq_bf, wp_bf);

    attn_kernel<<<B_ * G_, 384, LDS_BYTES, stream>>>(feats, gidx, gmask, wq_bf, wp_bf,
                                                     bproj, out, cnt);

    finalize_kernel<<<(B_ * NMAX * C_ / 4 + 255) / 256, 256, 0, stream>>>(feats, cnt, gamma, out);
}

// Round 3
// 755.476 us; speedup vs baseline: 1.1057x; 1.0380x over previous
//
#include <hip/hip_runtime.h>
#include <hip/hip_bf16.h>

#define B_   8
#define NMAX 8192
#define C_   384
#define G_   512
#define K_   32
#define H_   6
#define DH_  64
#define CAP_ 64

typedef short bvec8 __attribute__((ext_vector_type(8)));
typedef short bvec4 __attribute__((ext_vector_type(4)));
typedef _Float16 hvec4 __attribute__((ext_vector_type(4)));
typedef float f32x4 __attribute__((ext_vector_type(4)));

__device__ __forceinline__ short f2bf(float f) {
    union { __hip_bfloat16 b; short s; } u;
    u.b = __float2bfloat16(f);
    return u.s;
}
__device__ __forceinline__ float bf2f(unsigned short u) {
    union { unsigned int i; float f; } w;
    w.i = ((unsigned int)u) << 16;
    return w.f;
}
__device__ __forceinline__ unsigned char f2fp8(float x) {
    return (unsigned char)(__builtin_amdgcn_cvt_pk_fp8_f32(x, x, 0, false) & 0xff);
}

// ---- LDS layout (bytes) ----
// [0, 24576)        xg (later attn_out, later proj_out)  [32 rows][768 B] bf16, XOR-swizzled
// [24576 + h*4096)  qf8 [32][64] fp8 ; +2048: kf8 [32][64] fp8
// [49152) mask 32 f32 ; [49280) idx 32 i32
#define HB_OFF    24576
#define MASK_OFF  49152
#define IDX_OFF   49280
#define LDS_BYTES 49408

__device__ __forceinline__ int swzA(int row, int colb) { return row * 768 + (colb ^ ((row & 7) << 4)); }
__device__ __forceinline__ int swz8(int row, int col)  { return row * 64  + (col  ^ ((row & 7) << 3)); }

__global__ void convw_kernel(const float* __restrict__ wqkv, const float* __restrict__ wproj,
                             short* __restrict__ wq_bf, short* __restrict__ wp_bf) {
    int i = blockIdx.x * 256 + threadIdx.x;
    if (i < 3 * C_ * C_) wq_bf[i] = f2bf(wqkv[i]);
    if (i < C_ * C_)     wp_bf[i] = f2bf(wproj[i]);
}

// Build inverted index: per point, list of valid slot-ids (within batch).
__global__ void fill_kernel(const int* __restrict__ gidx, const float* __restrict__ gmask,
                            int* __restrict__ fillcnt, unsigned short* __restrict__ list) {
    int t = blockIdx.x * 256 + threadIdx.x;
    if (t >= B_ * G_ * K_) return;
    float m = gmask[t];
    if (m <= 0.f) return;
    int v = gidx[t];
    v = v < 0 ? 0 : v;
    int b = t >> 14;                      // t / (G*K) = t / 16384
    int bn = b * NMAX + v;
    int pos = atomicAdd(&fillcnt[bn], 1);
    if (pos < CAP_) list[(size_t)bn * CAP_ + pos] = (unsigned short)(t - (b << 14));
}

template<bool SLOT>
__global__ __launch_bounds__(384, 5) void attn_kernel(
    const float* __restrict__ feats, const int* __restrict__ gidx,
    const float* __restrict__ gmask, const short* __restrict__ wqkv,
    const short* __restrict__ wproj, const float* __restrict__ bproj,
    float* __restrict__ acc_out, float* __restrict__ cnt,
    short* __restrict__ slotbuf) {
    extern __shared__ char sm[];
    float* mask_lds = (float*)(sm + MASK_OFF);
    int*   idx_lds  = (int*)(sm + IDX_OFF);

    const int tid  = threadIdx.x;
    const int lane = tid & 63;
    const int h    = tid >> 6;          // wave id = head id (0..5)
    const int bg   = blockIdx.x;        // group id within [0, B*G)
    const int b    = bg >> 9;
    const int l15  = lane & 15;
    const int l4   = lane >> 4;

    if (tid < 32) {
        int v = gidx[(size_t)bg * K_ + tid];
        v = v < 0 ? 0 : v;
        float m = gmask[(size_t)bg * K_ + tid];
        idx_lds[tid]  = v;
        mask_lds[tid] = m;
        if (!SLOT) {
            if (m > 0.f) atomicAdd(&cnt[b * NMAX + v], m);
        }
    }
    __syncthreads();

    // ---- gather: 32 rows x 384 fp32 -> bf16 LDS (swizzled) ----
    #pragma unroll
    for (int i = 0; i < 8; ++i) {
        int p = i * 384 + tid;          // 0..3071 tasks, one float4 each
        int row = p / 96, seg = p % 96;
        float4 f = *(const float4*)(feats + ((size_t)(b * NMAX + idx_lds[row]) * C_ + seg * 4));
        bvec4 v4 = { f2bf(f.x), f2bf(f.y), f2bf(f.z), f2bf(f.w) };
        *(bvec4*)(sm + swzA(row, seg * 8)) = v4;
    }
    __syncthreads();

    char* qf = sm + HB_OFF + h * 4096;
    char* kf = qf + 2048;

    // ---- q and k GEMMs: [32 x 64] = xg[32x384] @ W^T  -> fp8 LDS ----
    for (int mat = 0; mat < 2; ++mat) {
        f32x4 acc[2][4];
        #pragma unroll
        for (int mt = 0; mt < 2; ++mt)
            #pragma unroll
            for (int nt = 0; nt < 4; ++nt) acc[mt][nt] = (f32x4){0.f, 0.f, 0.f, 0.f};
        const short* wb = wqkv + ((size_t)(mat * C_ + h * DH_)) * C_;
        #pragma unroll
        for (int kk = 0; kk < 12; ++kk) {
            bvec8 a0 = *(const bvec8*)(sm + swzA(l15,      kk * 64 + l4 * 16));
            bvec8 a1 = *(const bvec8*)(sm + swzA(16 + l15, kk * 64 + l4 * 16));
            #pragma unroll
            for (int nt = 0; nt < 4; ++nt) {
                bvec8 bf = *(const bvec8*)(wb + (size_t)(nt * 16 + l15) * C_ + kk * 32 + l4 * 8);
                acc[0][nt] = __builtin_amdgcn_mfma_f32_16x16x32_bf16(a0, bf, acc[0][nt], 0, 0, 0);
                acc[1][nt] = __builtin_amdgcn_mfma_f32_16x16x32_bf16(a1, bf, acc[1][nt], 0, 0, 0);
            }
        }
        char* dst = mat ? kf : qf;
        #pragma unroll
        for (int mt = 0; mt < 2; ++mt)
            #pragma unroll
            for (int nt = 0; nt < 4; ++nt)
                #pragma unroll
                for (int j = 0; j < 4; ++j) {
                    int r = mt * 16 + l4 * 4 + j, c = nt * 16 + l15;
                    *(unsigned char*)(dst + swz8(r, c)) = f2fp8(acc[mt][nt][j]);
                }
    }

    // ---- v GEMM: keep result in registers as f16 A-fragments ----
    hvec4 vfrag[2][4];
    {
        f32x4 acc[2][4];
        #pragma unroll
        for (int mt = 0; mt < 2; ++mt)
            #pragma unroll
            for (int nt = 0; nt < 4; ++nt) acc[mt][nt] = (f32x4){0.f, 0.f, 0.f, 0.f};
        const short* wb = wqkv + ((size_t)(2 * C_ + h * DH_)) * C_;
        #pragma unroll
        for (int kk = 0; kk < 12; ++kk) {
            bvec8 a0 = *(const bvec8*)(sm + swzA(l15,      kk * 64 + l4 * 16));
            bvec8 a1 = *(const bvec8*)(sm + swzA(16 + l15, kk * 64 + l4 * 16));
            #pragma unroll
            for (int nt = 0; nt < 4; ++nt) {
                bvec8 bf = *(const bvec8*)(wb + (size_t)(nt * 16 + l15) * C_ + kk * 32 + l4 * 8);
                acc[0][nt] = __builtin_amdgcn_mfma_f32_16x16x32_bf16(a0, bf, acc[0][nt], 0, 0, 0);
                acc[1][nt] = __builtin_amdgcn_mfma_f32_16x16x32_bf16(a1, bf, acc[1][nt], 0, 0, 0);
            }
        }
        #pragma unroll
        for (int mt = 0; mt < 2; ++mt)
            #pragma unroll
            for (int nt = 0; nt < 4; ++nt)
                vfrag[mt][nt] = (hvec4){ (_Float16)acc[mt][nt][0], (_Float16)acc[mt][nt][1],
                                         (_Float16)acc[mt][nt][2], (_Float16)acc[mt][nt][3] };
    }

    // ---- scores^T = k @ q^T  (fp8, [32 keys x 32 qtok]) ----
    f32x4 sc[2][2];
    #pragma unroll
    for (int mt = 0; mt < 2; ++mt)
        #pragma unroll
        for (int nt = 0; nt < 2; ++nt) sc[mt][nt] = (f32x4){0.f, 0.f, 0.f, 0.f};
    #pragma unroll
    for (int kk = 0; kk < 2; ++kk) {
        long ka0 = *(const long*)(kf + swz8(l15,      kk * 32 + l4 * 8));
        long ka1 = *(const long*)(kf + swz8(16 + l15, kk * 32 + l4 * 8));
        long qa0 = *(const long*)(qf + swz8(l15,      kk * 32 + l4 * 8));
        long qa1 = *(const long*)(qf + swz8(16 + l15, kk * 32 + l4 * 8));
        sc[0][0] = __builtin_amdgcn_mfma_f32_16x16x32_fp8_fp8(ka0, qa0, sc[0][0], 0, 0, 0);
        sc[0][1] = __builtin_amdgcn_mfma_f32_16x16x32_fp8_fp8(ka0, qa1, sc[0][1], 0, 0, 0);
        sc[1][0] = __builtin_amdgcn_mfma_f32_16x16x32_fp8_fp8(ka1, qa0, sc[1][0], 0, 0, 0);
        sc[1][1] = __builtin_amdgcn_mfma_f32_16x16x32_fp8_fp8(ka1, qa1, sc[1][1], 0, 0, 0);
    }

    // ---- softmax over keys (keys live in-register + across l4 groups) ----
    float bk[2][4];
    #pragma unroll
    for (int mt = 0; mt < 2; ++mt)
        #pragma unroll
        for (int j = 0; j < 4; ++j)
            bk[mt][j] = mask_lds[mt * 16 + l4 * 4 + j] > 0.f ? 0.f : -1e30f;

    hvec4 pfrag[2][2];   // [key chunk c][qtok tile qt]
    #pragma unroll
    for (int nt = 0; nt < 2; ++nt) {
        float s[2][4];
        float mx = -1e30f;
        #pragma unroll
        for (int mt = 0; mt < 2; ++mt)
            #pragma unroll
            for (int j = 0; j < 4; ++j) {
                s[mt][j] = sc[mt][nt][j] * 0.125f + bk[mt][j];
                mx = fmaxf(mx, s[mt][j]);
            }
        mx = fmaxf(mx, __shfl_xor(mx, 16));
        mx = fmaxf(mx, __shfl_xor(mx, 32));
        float sum = 0.f;
        #pragma unroll
        for (int mt = 0; mt < 2; ++mt)
            #pragma unroll
            for (int j = 0; j < 4; ++j) {
                s[mt][j] = __expf(s[mt][j] - mx);
                sum += s[mt][j];
            }
        sum += __shfl_xor(sum, 16);
        sum += __shfl_xor(sum, 32);
        float inv = 1.f / sum;
        #pragma unroll
        for (int mt = 0; mt < 2; ++mt)
            pfrag[mt][nt] = (hvec4){ (_Float16)(s[mt][0] * inv), (_Float16)(s[mt][1] * inv),
                                     (_Float16)(s[mt][2] * inv), (_Float16)(s[mt][3] * inv) };
    }

    // ---- PV: out^T[dh][qtok] via 16x16x16 f16 MFMA, all in registers ----
    f32x4 po[4][2];
    #pragma unroll
    for (int dt = 0; dt < 4; ++dt)
        #pragma unroll
        for (int qt = 0; qt < 2; ++qt) po[dt][qt] = (f32x4){0.f, 0.f, 0.f, 0.f};
    #pragma unroll
    for (int c = 0; c < 2; ++c)
        #pragma unroll
        for (int dt = 0; dt < 4; ++dt)
            #pragma unroll
            for (int qt = 0; qt < 2; ++qt)
                po[dt][qt] = __builtin_amdgcn_mfma_f32_16x16x16f16(vfrag[c][dt], pfrag[c][qt], po[dt][qt], 0, 0, 0);

    __syncthreads();   // all waves done reading xg (v-GEMM) before overwrite

    // write attn_out (bf16) into xg buffer: out^T C-layout -> [tok][channel]
    #pragma unroll
    for (int dt = 0; dt < 4; ++dt)
        #pragma unroll
        for (int qt = 0; qt < 2; ++qt)
            #pragma unroll
            for (int j = 0; j < 4; ++j) {
                int tok = qt * 16 + l15;
                int ch  = h * DH_ + dt * 16 + l4 * 4 + j;
                *(short*)(sm + swzA(tok, ch * 2)) = f2bf(po[dt][qt][j]);
            }
    __syncthreads();

    // ---- proj: out[32 x 384] = attn_out @ w_proj^T ; wave h -> cols h*64.. ----
    f32x4 pr[2][4];
    #pragma unroll
    for (int mt = 0; mt < 2; ++mt)
        #pragma unroll
        for (int nt = 0; nt < 4; ++nt) pr[mt][nt] = (f32x4){0.f, 0.f, 0.f, 0.f};
    #pragma unroll
    for (int kk = 0; kk < 12; ++kk) {
        bvec8 a0 = *(const bvec8*)(sm + swzA(l15,      kk * 64 + l4 * 16));
        bvec8 a1 = *(const bvec8*)(sm + swzA(16 + l15, kk * 64 + l4 * 16));
        #pragma unroll
        for (int nt = 0; nt < 4; ++nt) {
            bvec8 w = *(const bvec8*)(wproj + (size_t)(h * DH_ + nt * 16 + l15) * C_ + kk * 32 + l4 * 8);
            pr[0][nt] = __builtin_amdgcn_mfma_f32_16x16x32_bf16(a0, w, pr[0][nt], 0, 0, 0);
            pr[1][nt] = __builtin_amdgcn_mfma_f32_16x16x32_bf16(a1, w, pr[1][nt], 0, 0, 0);
        }
    }

    if constexpr (SLOT) {
        // ---- write proj+bias rows (bf16) to slot buffer via LDS (coalesced) ----
        __syncthreads();   // all proj MFMA reads of xg complete
        #pragma unroll
        for (int nt = 0; nt < 4; ++nt) {
            int c = h * DH_ + nt * 16 + l15;
            float bias = bproj[c];
            #pragma unroll
            for (int mt = 0; mt < 2; ++mt)
                #pragma unroll
                for (int j = 0; j < 4; ++j) {
                    int t = mt * 16 + l4 * 4 + j;
                    *(short*)(sm + swzA(t, c * 2)) = f2bf(pr[mt][nt][j] + bias);
                }
        }
        __syncthreads();
        #pragma unroll
        for (int i = 0; i < 4; ++i) {
            int chunk = i * 384 + tid;          // 1536 chunks of 16B
            int row = chunk / 48, off = chunk % 48;
            bvec8 v = *(const bvec8*)(sm + swzA(row, off * 16));
            *(bvec8*)(slotbuf + ((size_t)(bg * K_ + row)) * C_ + off * 8) = v;
        }
    } else {
        // ---- masked scatter-add into acc (d_out) ----
        #pragma unroll
        for (int nt = 0; nt < 4; ++nt) {
            int c = h * DH_ + nt * 16 + l15;
            float bias = bproj[c];
            #pragma unroll
            for (int mt = 0; mt < 2; ++mt)
                #pragma unroll
                for (int j = 0; j < 4; ++j) {
                    int t = mt * 16 + l4 * 4 + j;
                    float mk = mask_lds[t];
                    if (mk > 0.f) {
                        float val = pr[mt][nt][j] + bias;
                        atomicAdd(acc_out + (size_t)(b * NMAX + idx_lds[t]) * C_ + c, val);
                    }
                }
        }
    }
}

// Path A finalize: block per point, gather slot rows, average, add residual.
__global__ __launch_bounds__(192) void finalize2_kernel(
    const float* __restrict__ feats, const int* __restrict__ fillcnt,
    const unsigned short* __restrict__ list, const short* __restrict__ slotbuf,
    const float* __restrict__ gamma, float* __restrict__ out) {
    int bn = blockIdx.x;               // b * NMAX + n
    int b  = bn >> 13;
    int tid = threadIdx.x;             // 0..191, handles channel pair tid*2
    int c = fillcnt[bn];
    int cc = c < CAP_ ? c : CAP_;
    float ax = 0.f, ay = 0.f;
    const unsigned int* sb = (const unsigned int*)slotbuf;
    for (int e = 0; e < cc; ++e) {
        int sl = list[(size_t)bn * CAP_ + e];
        unsigned int w = sb[((size_t)(b << 14) + sl) * (C_ / 2) + tid];
        ax += bf2f((unsigned short)(w & 0xffff));
        ay += bf2f((unsigned short)(w >> 16));
    }
    float inv = 1.f / (float)(c < 1 ? 1 : c);
    size_t o = (size_t)bn * C_ + tid * 2;
    float2 f = *(const float2*)(feats + o);
    float gx = gamma[tid * 2], gy = gamma[tid * 2 + 1];
    float2 r;
    r.x = f.x + ax * inv * gx;
    r.y = f.y + ay * inv * gy;
    *(float2*)(out + o) = r;
}

// Path B finalize (fallback): out already holds atomic accumulator.
__global__ void finalize_kernel(const float* __restrict__ feats, const float* __restrict__ cnt,
                                const float* __restrict__ gamma, float* __restrict__ out) {
    size_t i4 = (size_t)blockIdx.x * 256 + threadIdx.x;       // float4 index
    const size_t total4 = (size_t)B_ * NMAX * C_ / 4;
    if (i4 >= total4) return;
    int n  = (int)(i4 / (C_ / 4));
    int c4 = (int)(i4 % (C_ / 4)) * 4;
    float cv = cnt[n];
    float inv = 1.f / (cv < 1.f ? 1.f : cv);
    float4 a = ((const float4*)out)[i4];
    float4 f = ((const float4*)feats)[i4];
    float4 g = *(const float4*)(gamma + c4);
    float4 r;
    r.x = f.x + a.x * inv * g.x;
    r.y = f.y + a.y * inv * g.y;
    r.z = f.z + a.z * inv * g.z;
    r.w = f.w + a.w * inv * g.w;
    ((float4*)out)[i4] = r;
}

extern "C" void kernel_launch(void* const* d_in, const int* in_sizes, int n_in,
                              void* d_out, int out_size, void* d_ws, size_t ws_size,
                              hipStream_t stream) {
    const float* feats = (const float*)d_in[0];
    const int*   gidx  = (const int*)d_in[1];
    const float* gmask = (const float*)d_in[2];
    const float* wqkv  = (const float*)d_in[3];
    const float* wproj = (const float*)d_in[4];
    const float* bproj = (const float*)d_in[5];
    const float* gamma = (const float*)d_in[6];
    float* out = (float*)d_out;

    char* ws = (char*)d_ws;
    short* wq_bf = (short*)ws;                              // 884736 B
    short* wp_bf = (short*)(ws + 884736);                   // 294912 B
    // Path A layout:
    int*            fillcnt = (int*)(ws + 1179648);         // 262144 B
    unsigned short* list    = (unsigned short*)(ws + 1441792);        // 8 MiB
    short*          slotbuf = (short*)(ws + 1441792 + (size_t)B_*NMAX*CAP_*2); // ~100.7 MB
    const size_t neededA = 1441792 + (size_t)B_*NMAX*CAP_*2 + (size_t)B_*G_*K_*C_*2;
    // Path B layout (fallback):
    float* cnt = (float*)(ws + 1179648);

    convw_kernel<<<(3 * C_ * C_ + 255) / 256, 256, 0, stream>>>(wqkv, wproj, wq_bf, wp_bf);

    if (ws_size >= neededA) {
        hipMemsetAsync(fillcnt, 0, (size_t)B_ * NMAX * sizeof(int), stream);
        fill_kernel<<<(B_ * G_ * K_ + 255) / 256, 256, 0, stream>>>(gidx, gmask, fillcnt, list);
        attn_kernel<true><<<B_ * G_, 384, LDS_BYTES, stream>>>(feats, gidx, gmask, wq_bf, wp_bf,
                                                               bproj, out, nullptr, slotbuf);
        finalize2_kernel<<<B_ * NMAX, 192, 0, stream>>>(feats, fillcnt, list, slotbuf, gamma, out);
    } else {
        hipMemsetAsync(out, 0, (size_t)B_ * NMAX * C_ * sizeof(float), stream);
        hipMemsetAsync(cnt, 0, (size_t)B_ * NMAX * sizeof(float), stream);
        attn_kernel<false><<<B_ * G_, 384, LDS_BYTES, stream>>>(feats, gidx, gmask, wq_bf, wp_bf,
                                                                bproj, out, cnt, nullptr);
        finalize_kernel<<<(B_ * NMAX * C_ / 4 + 255) / 256, 256, 0, stream>>>(feats, cnt, gamma, out);
    }
}

// Round 4
// 704.748 us; speedup vs baseline: 1.1852x; 1.0720x over previous
//
#include <hip/hip_runtime.h>
#include <hip/hip_bf16.h>

#define B_   8
#define NMAX 8192
#define C_   384
#define G_   512
#define K_   32
#define H_   6
#define DH_  64
#define CAP_ 64

typedef short bvec8 __attribute__((ext_vector_type(8)));
typedef short bvec4 __attribute__((ext_vector_type(4)));
typedef _Float16 hvec4 __attribute__((ext_vector_type(4)));
typedef float f32x4 __attribute__((ext_vector_type(4)));

__device__ __forceinline__ short f2bf(float f) {
    union { __hip_bfloat16 b; short s; } u;
    u.b = __float2bfloat16(f);
    return u.s;
}
__device__ __forceinline__ float bf2f(unsigned short u) {
    union { unsigned int i; float f; } w;
    w.i = ((unsigned int)u) << 16;
    return w.f;
}
__device__ __forceinline__ unsigned char f2fp8(float x) {
    return (unsigned char)(__builtin_amdgcn_cvt_pk_fp8_f32(x, x, 0, false) & 0xff);
}

// ---- LDS layout (bytes) ----
// [0, 24576)        xg [32 rows][768 B] bf16, XOR-swizzled (swzA). Input tokens; never overwritten
//                   until the proj-output staging at the very end (SLOT epilogue).
// [24576 + h*4096)  per-head region, wave-private:
//                     phase 1: qf8 [32][64B] fp8 (swz8) at +0, kf8 at +2048
//                     phase 2 (after scores): attn_out stage [32 tok][128 B] bf16 (swzQ)
// [49152) mask 32 f32 ; [49280) idx 32 i32
#define HB_OFF    24576
#define MASK_OFF  49152
#define IDX_OFF   49280
#define LDS_BYTES 49408

__device__ __forceinline__ int swzA(int row, int colb) { return row * 768 + (colb ^ ((row & 7) << 4)); }
__device__ __forceinline__ int swzQ(int row, int colb) { return row * 128 + (colb ^ ((row & 7) << 4)); }
__device__ __forceinline__ int swz8(int row, int col)  { return row * 64  + (col  ^ ((row & 7) << 3)); }

__global__ void convw_kernel(const float* __restrict__ wqkv, const float* __restrict__ wproj,
                             short* __restrict__ wq_bf, short* __restrict__ wp_bf) {
    int i = blockIdx.x * 256 + threadIdx.x;
    if (i < 3 * C_ * C_) wq_bf[i] = f2bf(wqkv[i]);
    if (i < C_ * C_)     wp_bf[i] = f2bf(wproj[i]);
}

// Build inverted index: per point, list of valid slot-ids (within batch).
__global__ void fill_kernel(const int* __restrict__ gidx, const float* __restrict__ gmask,
                            int* __restrict__ fillcnt, unsigned short* __restrict__ list) {
    int t = blockIdx.x * 256 + threadIdx.x;
    if (t >= B_ * G_ * K_) return;
    float m = gmask[t];
    if (m <= 0.f) return;
    int v = gidx[t];
    v = v < 0 ? 0 : v;
    int b = t >> 14;                      // t / (G*K)
    int bn = b * NMAX + v;
    int pos = atomicAdd(&fillcnt[bn], 1);
    if (pos < CAP_) list[(size_t)bn * CAP_ + pos] = (unsigned short)(t - (b << 14));
}

template<bool SLOT>
__global__ __launch_bounds__(384, 4) void attn_kernel(
    const float* __restrict__ feats, const int* __restrict__ gidx,
    const float* __restrict__ gmask, const short* __restrict__ wqkv,
    const short* __restrict__ wproj, const float* __restrict__ bproj,
    float* __restrict__ acc_out, float* __restrict__ cnt,
    short* __restrict__ slotbuf) {
    extern __shared__ char sm[];
    float* mask_lds = (float*)(sm + MASK_OFF);
    int*   idx_lds  = (int*)(sm + IDX_OFF);

    const int tid  = threadIdx.x;
    const int lane = tid & 63;
    const int h    = tid >> 6;          // wave id = head id (0..5)
    const int bg   = blockIdx.x;        // group id within [0, B*G)
    const int b    = bg >> 9;
    const int l15  = lane & 15;
    const int l4   = lane >> 4;

    if (tid < 32) {
        int v = gidx[(size_t)bg * K_ + tid];
        v = v < 0 ? 0 : v;
        float m = gmask[(size_t)bg * K_ + tid];
        idx_lds[tid]  = v;
        mask_lds[tid] = m;
        if (!SLOT) {
            if (m > 0.f) atomicAdd(&cnt[b * NMAX + v], m);
        }
    }
    __syncthreads();

    // ---- gather: 32 rows x 384 fp32 -> bf16 LDS (swizzled) ----
    #pragma unroll
    for (int i = 0; i < 8; ++i) {
        int p = i * 384 + tid;          // 3072 tasks, one float4 each
        int row = p / 96, seg = p % 96;
        float4 f = *(const float4*)(feats + ((size_t)(b * NMAX + idx_lds[row]) * C_ + seg * 4));
        bvec4 v4 = { f2bf(f.x), f2bf(f.y), f2bf(f.z), f2bf(f.w) };
        *(bvec4*)(sm + swzA(row, seg * 8)) = v4;
    }
    __syncthreads();

    char* hb = sm + HB_OFF + h * 4096;   // wave-private head region
    char* qf = hb;
    char* kf = hb + 2048;

    // ---- q and k GEMMs: [32 x 64] = xg[32x384] @ W^T  -> fp8 LDS ----
    for (int mat = 0; mat < 2; ++mat) {
        f32x4 acc[2][4];
        #pragma unroll
        for (int mt = 0; mt < 2; ++mt)
            #pragma unroll
            for (int nt = 0; nt < 4; ++nt) acc[mt][nt] = (f32x4){0.f, 0.f, 0.f, 0.f};
        const short* wb = wqkv + ((size_t)(mat * C_ + h * DH_)) * C_;
        #pragma unroll
        for (int kk = 0; kk < 12; ++kk) {
            bvec8 a0 = *(const bvec8*)(sm + swzA(l15,      kk * 64 + l4 * 16));
            bvec8 a1 = *(const bvec8*)(sm + swzA(16 + l15, kk * 64 + l4 * 16));
            #pragma unroll
            for (int nt = 0; nt < 4; ++nt) {
                bvec8 bf = *(const bvec8*)(wb + (size_t)(nt * 16 + l15) * C_ + kk * 32 + l4 * 8);
                acc[0][nt] = __builtin_amdgcn_mfma_f32_16x16x32_bf16(a0, bf, acc[0][nt], 0, 0, 0);
                acc[1][nt] = __builtin_amdgcn_mfma_f32_16x16x32_bf16(a1, bf, acc[1][nt], 0, 0, 0);
            }
        }
        char* dst = mat ? kf : qf;
        #pragma unroll
        for (int mt = 0; mt < 2; ++mt)
            #pragma unroll
            for (int nt = 0; nt < 4; ++nt)
                #pragma unroll
                for (int j = 0; j < 4; ++j) {
                    int r = mt * 16 + l4 * 4 + j, c = nt * 16 + l15;
                    *(unsigned char*)(dst + swz8(r, c)) = f2fp8(acc[mt][nt][j]);
                }
    }

    // ---- scores^T = k @ q^T  (fp8, [32 keys x 32 qtok]) ----
    f32x4 sc[2][2];
    #pragma unroll
    for (int mt = 0; mt < 2; ++mt)
        #pragma unroll
        for (int nt = 0; nt < 2; ++nt) sc[mt][nt] = (f32x4){0.f, 0.f, 0.f, 0.f};
    #pragma unroll
    for (int kk = 0; kk < 2; ++kk) {
        long ka0 = *(const long*)(kf + swz8(l15,      kk * 32 + l4 * 8));
        long ka1 = *(const long*)(kf + swz8(16 + l15, kk * 32 + l4 * 8));
        long qa0 = *(const long*)(qf + swz8(l15,      kk * 32 + l4 * 8));
        long qa1 = *(const long*)(qf + swz8(16 + l15, kk * 32 + l4 * 8));
        sc[0][0] = __builtin_amdgcn_mfma_f32_16x16x32_fp8_fp8(ka0, qa0, sc[0][0], 0, 0, 0);
        sc[0][1] = __builtin_amdgcn_mfma_f32_16x16x32_fp8_fp8(ka0, qa1, sc[0][1], 0, 0, 0);
        sc[1][0] = __builtin_amdgcn_mfma_f32_16x16x32_fp8_fp8(ka1, qa0, sc[1][0], 0, 0, 0);
        sc[1][1] = __builtin_amdgcn_mfma_f32_16x16x32_fp8_fp8(ka1, qa1, sc[1][1], 0, 0, 0);
    }

    // ---- softmax over keys (keys in-register + across l4 groups) ----
    // lane holds scT[key = mt*16 + l4*4 + j][qtok = nt*16 + l15]
    float bk[2][4];
    #pragma unroll
    for (int mt = 0; mt < 2; ++mt)
        #pragma unroll
        for (int j = 0; j < 4; ++j)
            bk[mt][j] = mask_lds[mt * 16 + l4 * 4 + j] > 0.f ? 0.f : -1e30f;

    hvec4 pfrag[2][2];   // [key chunk c][qtok tile qt]
    #pragma unroll
    for (int nt = 0; nt < 2; ++nt) {
        float s[2][4];
        float mx = -1e30f;
        #pragma unroll
        for (int mt = 0; mt < 2; ++mt)
            #pragma unroll
            for (int j = 0; j < 4; ++j) {
                s[mt][j] = sc[mt][nt][j] * 0.125f + bk[mt][j];
                mx = fmaxf(mx, s[mt][j]);
            }
        mx = fmaxf(mx, __shfl_xor(mx, 16));
        mx = fmaxf(mx, __shfl_xor(mx, 32));
        float sum = 0.f;
        #pragma unroll
        for (int mt = 0; mt < 2; ++mt)
            #pragma unroll
            for (int j = 0; j < 4; ++j) {
                s[mt][j] = __expf(s[mt][j] - mx);
                sum += s[mt][j];
            }
        sum += __shfl_xor(sum, 16);
        sum += __shfl_xor(sum, 32);
        float inv = 1.f / sum;
        #pragma unroll
        for (int mt = 0; mt < 2; ++mt)
            pfrag[mt][nt] = (hvec4){ (_Float16)(s[mt][0] * inv), (_Float16)(s[mt][1] * inv),
                                     (_Float16)(s[mt][2] * inv), (_Float16)(s[mt][3] * inv) };
    }

    // ---- v-GEMM + PV in two dh-halves (keeps register peak low) ----
    // After scores, the q/k fp8 region is dead; reuse hb as attn_out stage:
    // [32 tok][128 B] bf16, swzQ. Wave-private -> no barrier needed.
    #pragma unroll
    for (int dtH = 0; dtH < 2; ++dtH) {
        f32x4 accv[2][2];
        #pragma unroll
        for (int mt = 0; mt < 2; ++mt)
            #pragma unroll
            for (int n2 = 0; n2 < 2; ++n2) accv[mt][n2] = (f32x4){0.f, 0.f, 0.f, 0.f};
        const short* wb = wqkv + ((size_t)(2 * C_ + h * DH_ + dtH * 32)) * C_;
        #pragma unroll
        for (int kk = 0; kk < 12; ++kk) {
            bvec8 a0 = *(const bvec8*)(sm + swzA(l15,      kk * 64 + l4 * 16));
            bvec8 a1 = *(const bvec8*)(sm + swzA(16 + l15, kk * 64 + l4 * 16));
            #pragma unroll
            for (int n2 = 0; n2 < 2; ++n2) {
                bvec8 bf = *(const bvec8*)(wb + (size_t)(n2 * 16 + l15) * C_ + kk * 32 + l4 * 8);
                accv[0][n2] = __builtin_amdgcn_mfma_f32_16x16x32_bf16(a0, bf, accv[0][n2], 0, 0, 0);
                accv[1][n2] = __builtin_amdgcn_mfma_f32_16x16x32_bf16(a1, bf, accv[1][n2], 0, 0, 0);
            }
        }
        hvec4 vfrag[2][2];
        #pragma unroll
        for (int mt = 0; mt < 2; ++mt)
            #pragma unroll
            for (int n2 = 0; n2 < 2; ++n2)
                vfrag[mt][n2] = (hvec4){ (_Float16)accv[mt][n2][0], (_Float16)accv[mt][n2][1],
                                         (_Float16)accv[mt][n2][2], (_Float16)accv[mt][n2][3] };
        f32x4 po[2][2];
        #pragma unroll
        for (int d2 = 0; d2 < 2; ++d2)
            #pragma unroll
            for (int qt = 0; qt < 2; ++qt) po[d2][qt] = (f32x4){0.f, 0.f, 0.f, 0.f};
        #pragma unroll
        for (int c = 0; c < 2; ++c)
            #pragma unroll
            for (int d2 = 0; d2 < 2; ++d2)
                #pragma unroll
                for (int qt = 0; qt < 2; ++qt)
                    po[d2][qt] = __builtin_amdgcn_mfma_f32_16x16x16f16(vfrag[c][d2], pfrag[c][qt], po[d2][qt], 0, 0, 0);
        // stage attn_out: tok = qt*16+l15, ch = dtH*32 + d2*16 + l4*4 + j
        #pragma unroll
        for (int d2 = 0; d2 < 2; ++d2)
            #pragma unroll
            for (int qt = 0; qt < 2; ++qt)
                #pragma unroll
                for (int j = 0; j < 4; ++j) {
                    int tok = qt * 16 + l15;
                    int ch  = dtH * 32 + d2 * 16 + l4 * 4 + j;
                    *(short*)(hb + swzQ(tok, ch * 2)) = f2bf(po[d2][qt][j]);
                }
    }
    __syncthreads();   // all heads' attn_out staged before proj reads across heads

    // ---- proj: out[32 x 384] = attn_out @ w_proj^T ; wave h -> cols h*64.. ----
    // A-fragments read from per-head stage buffers: ch = kk*32 + l4*8 -> head kk>>1
    f32x4 pr[2][4];
    #pragma unroll
    for (int mt = 0; mt < 2; ++mt)
        #pragma unroll
        for (int nt = 0; nt < 4; ++nt) pr[mt][nt] = (f32x4){0.f, 0.f, 0.f, 0.f};
    #pragma unroll
    for (int kk = 0; kk < 12; ++kk) {
        const char* st = sm + HB_OFF + (kk >> 1) * 4096;
        int colb = (kk & 1) * 64 + l4 * 16;
        bvec8 a0 = *(const bvec8*)(st + swzQ(l15,      colb));
        bvec8 a1 = *(const bvec8*)(st + swzQ(16 + l15, colb));
        #pragma unroll
        for (int nt = 0; nt < 4; ++nt) {
            bvec8 w = *(const bvec8*)(wproj + (size_t)(h * DH_ + nt * 16 + l15) * C_ + kk * 32 + l4 * 8);
            pr[0][nt] = __builtin_amdgcn_mfma_f32_16x16x32_bf16(a0, w, pr[0][nt], 0, 0, 0);
            pr[1][nt] = __builtin_amdgcn_mfma_f32_16x16x32_bf16(a1, w, pr[1][nt], 0, 0, 0);
        }
    }

    if constexpr (SLOT) {
        // xg region is free now (last read was v-GEMM, all waves past the stage barrier).
        #pragma unroll
        for (int nt = 0; nt < 4; ++nt) {
            int c = h * DH_ + nt * 16 + l15;
            float bias = bproj[c];
            #pragma unroll
            for (int mt = 0; mt < 2; ++mt)
                #pragma unroll
                for (int j = 0; j < 4; ++j) {
                    int t = mt * 16 + l4 * 4 + j;
                    *(short*)(sm + swzA(t, c * 2)) = f2bf(pr[mt][nt][j] + bias);
                }
        }
        __syncthreads();
        #pragma unroll
        for (int i = 0; i < 4; ++i) {
            int chunk = i * 384 + tid;          // 1536 chunks of 16B
            int row = chunk / 48, off = chunk % 48;
            bvec8 v = *(const bvec8*)(sm + swzA(row, off * 16));
            *(bvec8*)(slotbuf + ((size_t)(bg * K_ + row)) * C_ + off * 8) = v;
        }
    } else {
        // ---- masked scatter-add into acc (d_out) ----
        #pragma unroll
        for (int nt = 0; nt < 4; ++nt) {
            int c = h * DH_ + nt * 16 + l15;
            float bias = bproj[c];
            #pragma unroll
            for (int mt = 0; mt < 2; ++mt)
                #pragma unroll
                for (int j = 0; j < 4; ++j) {
                    int t = mt * 16 + l4 * 4 + j;
                    float mk = mask_lds[t];
                    if (mk > 0.f) {
                        float val = pr[mt][nt][j] + bias;
                        atomicAdd(acc_out + (size_t)(b * NMAX + idx_lds[t]) * C_ + c, val);
                    }
                }
        }
    }
}

// Path A finalize: block per point, gather slot rows, average, add residual.
__global__ __launch_bounds__(192) void finalize2_kernel(
    const float* __restrict__ feats, const int* __restrict__ fillcnt,
    const unsigned short* __restrict__ list, const short* __restrict__ slotbuf,
    const float* __restrict__ gamma, float* __restrict__ out) {
    int bn = blockIdx.x;               // b * NMAX + n
    int b  = bn >> 13;
    int tid = threadIdx.x;             // 0..191, channel pair tid*2
    int c = fillcnt[bn];
    int cc = c < CAP_ ? c : CAP_;
    float ax = 0.f, ay = 0.f;
    const unsigned int* sb = (const unsigned int*)slotbuf;
    for (int e = 0; e < cc; ++e) {
        int sl = list[(size_t)bn * CAP_ + e];
        unsigned int w = sb[((size_t)(b << 14) + sl) * (C_ / 2) + tid];
        ax += bf2f((unsigned short)(w & 0xffff));
        ay += bf2f((unsigned short)(w >> 16));
    }
    float inv = 1.f / (float)(c < 1 ? 1 : c);
    size_t o = (size_t)bn * C_ + tid * 2;
    float2 f = *(const float2*)(feats + o);
    float gx = gamma[tid * 2], gy = gamma[tid * 2 + 1];
    float2 r;
    r.x = f.x + ax * inv * gx;
    r.y = f.y + ay * inv * gy;
    *(float2*)(out + o) = r;
}

// Path B finalize (fallback): out already holds atomic accumulator.
__global__ void finalize_kernel(const float* __restrict__ feats, const float* __restrict__ cnt,
                                const float* __restrict__ gamma, float* __restrict__ out) {
    size_t i4 = (size_t)blockIdx.x * 256 + threadIdx.x;
    const size_t total4 = (size_t)B_ * NMAX * C_ / 4;
    if (i4 >= total4) return;
    int n  = (int)(i4 / (C_ / 4));
    int c4 = (int)(i4 % (C_ / 4)) * 4;
    float cv = cnt[n];
    float inv = 1.f / (cv < 1.f ? 1.f : cv);
    float4 a = ((const float4*)out)[i4];
    float4 f = ((const float4*)feats)[i4];
    float4 g = *(const float4*)(gamma + c4);
    float4 r;
    r.x = f.x + a.x * inv * g.x;
    r.y = f.y + a.y * inv * g.y;
    r.z = f.z + a.z * inv * g.z;
    r.w = f.w + a.w * inv * g.w;
    ((float4*)out)[i4] = r;
}

extern "C" void kernel_launch(void* const* d_in, const int* in_sizes, int n_in,
                              void* d_out, int out_size, void* d_ws, size_t ws_size,
                              hipStream_t stream) {
    const float* feats = (const float*)d_in[0];
    const int*   gidx  = (const int*)d_in[1];
    const float* gmask = (const float*)d_in[2];
    const float* wqkv  = (const float*)d_in[3];
    const float* wproj = (const float*)d_in[4];
    const float* bproj = (const float*)d_in[5];
    const float* gamma = (const float*)d_in[6];
    float* out = (float*)d_out;

    char* ws = (char*)d_ws;
    short* wq_bf = (short*)ws;                              // 884736 B
    short* wp_bf = (short*)(ws + 884736);                   // 294912 B
    // Path A layout:
    int*            fillcnt = (int*)(ws + 1179648);         // 262144 B
    unsigned short* list    = (unsigned short*)(ws + 1441792);                 // 16 MiB
    short*          slotbuf = (short*)(ws + 1441792 + (size_t)B_*NMAX*CAP_*2); // ~100.7 MB
    const size_t neededA = 1441792 + (size_t)B_*NMAX*CAP_*2 + (size_t)B_*G_*K_*C_*2;
    // Path B layout (fallback):
    float* cnt = (float*)(ws + 1179648);

    convw_kernel<<<(3 * C_ * C_ + 255) / 256, 256, 0, stream>>>(wqkv, wproj, wq_bf, wp_bf);

    if (ws_size >= neededA) {
        hipMemsetAsync(fillcnt, 0, (size_t)B_ * NMAX * sizeof(int), stream);
        fill_kernel<<<(B_ * G_ * K_ + 255) / 256, 256, 0, stream>>>(gidx, gmask, fillcnt, list);
        attn_kernel<true><<<B_ * G_, 384, LDS_BYTES, stream>>>(feats, gidx, gmask, wq_bf, wp_bf,
                                                               bproj, out, nullptr, slotbuf);
        finalize2_kernel<<<B_ * NMAX, 192, 0, stream>>>(feats, fillcnt, list, slotbuf, gamma, out);
    } else {
        hipMemsetAsync(out, 0, (size_t)B_ * NMAX * C_ * sizeof(float), stream);
        hipMemsetAsync(cnt, 0, (size_t)B_ * NMAX * sizeof(float), stream);
        attn_kernel<false><<<B_ * G_, 384, LDS_BYTES, stream>>>(feats, gidx, gmask, wq_bf, wp_bf,
                                                                bproj, out, cnt, nullptr);
        finalize_kernel<<<(B_ * NMAX * C_ / 4 + 255) / 256, 256, 0, stream>>>(feats, cnt, gamma, out);
    }
}